// Round 4
// baseline (98.804 us; speedup 1.0000x reference)
//
#include <hip/hip_runtime.h>

#define HH 2048
#define WW 2048
#define KK 7
#define PADK 3
#define TILE 32
#define PADT 38              // rows of padded tile
#define INW 40               // sIn float cols: global tileC-4 .. tileC+35
#define INW4 (INW / 4)       // 10 float4 per row
#define HSW 36               // sHs/sHx float stride (mult of 4, not pow2)
#define HSW4 (HSW / 4)

typedef float v4f __attribute__((ext_vector_type(4)));

__global__ __launch_bounds__(256)
void UnfoldPlainFit_42477226558039_kernel(const float* __restrict__ x,
                                          float* __restrict__ out) {
    __shared__ float sIn[PADT][INW];   // 6080 B
    __shared__ float sHs[PADT][HSW];   // 5472 B
    __shared__ float sHx[PADT][HSW];   // 5472 B  -> 17 KB total, ~8 blk/CU

    const int bx = blockIdx.x, by = blockIdx.y;
    const int tileR = by * TILE, tileC = bx * TILE;
    const int tid = threadIdx.x;

    // ---- Stage 1: stage 38x40 window (global cols tileC-4 .. tileC+35) ----
    if (bx > 0 && bx < (WW / TILE - 1)) {
        // interior: fully in-range columns, 16B-aligned float4 path
#pragma unroll 2
        for (int idx = tid; idx < PADT * INW4; idx += 256) {
            int lr = idx / INW4;
            int k  = idx - lr * INW4;
            int gr = tileR - PADK + lr;
            gr = max(0, min(HH - 1, gr));        // row replication pad
            const v4f* src =
                reinterpret_cast<const v4f*>(x + (size_t)gr * WW + (tileC - 4)) + k;
            reinterpret_cast<v4f*>(&sIn[lr][0])[k] = *src;
        }
    } else {
        // column-edge tiles: scalar clamped path (128 of 4096 blocks)
        for (int idx = tid; idx < PADT * INW; idx += 256) {
            int lr = idx / INW;
            int lc = idx - lr * INW;
            int gr = max(0, min(HH - 1, tileR - PADK + lr));
            int gc = max(0, min(WW - 1, tileC - 4 + lc));
            sIn[lr][lc] = x[(size_t)gr * WW + gc];
        }
    }
    __syncthreads();

    // ---- Stage 2: horizontal sums, 4 outputs/thread via b128 reads ----
    // output col oc=4u+t needs sIn cols oc+1..oc+7; loads cover 4u..4u+11.
#pragma unroll 2
    for (int idx = tid; idx < PADT * 8; idx += 256) {
        int lr = idx >> 3;
        int u  = idx & 7;
        const v4f* row4 = reinterpret_cast<const v4f*>(&sIn[lr][0]);
        v4f a = row4[u], b = row4[u + 1], c = row4[u + 2];
        float w[12] = {a.x, a.y, a.z, a.w, b.x, b.y, b.z, b.w, c.x, c.y, c.z, c.w};
        v4f hs, hx;
#pragma unroll
        for (int t = 0; t < 4; ++t) {
            float s = 0.f, wx = 0.f;
#pragma unroll
            for (int m = 0; m < KK; ++m) {       // weight = m-3 for w[1+t+m]
                float v = w[1 + t + m];
                s += v;
                wx = fmaf((float)(m - PADK), v, wx);
            }
            hs[t] = s;
            hx[t] = wx;
        }
        reinterpret_cast<v4f*>(&sHs[lr][0])[u] = hs;
        reinterpret_cast<v4f*>(&sHx[lr][0])[u] = hx;
    }
    __syncthreads();

    // ---- Stage 3: vertical combine, 1x4 strip/thread, b128 LDS reads ----
    const int row = tid >> 3;          // 0..31
    const int u   = tid & 7;           // float4 group 0..7
    float c0[4] = {0.f, 0.f, 0.f, 0.f};
    float c1[4] = {0.f, 0.f, 0.f, 0.f};
    float c2[4] = {0.f, 0.f, 0.f, 0.f};
#pragma unroll
    for (int i = 0; i < KK; ++i) {
        v4f hs = reinterpret_cast<const v4f*>(&sHs[row + i][0])[u];
        v4f hx = reinterpret_cast<const v4f*>(&sHx[row + i][0])[u];
        float wy = (float)(i - PADK);
#pragma unroll
        for (int t = 0; t < 4; ++t) {
            c2[t] += hs[t];
            c1[t] = fmaf(wy, hs[t], c1[t]);
            c0[t] += hx[t];
        }
    }
    const float W196 = 1.0f / 196.0f;   // sum(x^2) over 7x7 = 196
    const float W49  = 1.0f / 49.0f;

    float* o = out + ((size_t)(tileR + row) * WW + tileC + 4 * u) * 3;
    v4f v0 = {c0[0] * W196, c1[0] * W196, c2[0] * W49,  c0[1] * W196};
    v4f v1 = {c1[1] * W196, c2[1] * W49,  c0[2] * W196, c1[2] * W196};
    v4f v2 = {c2[2] * W49,  c0[3] * W196, c1[3] * W196, c2[3] * W49};
    v4f* o4 = reinterpret_cast<v4f*>(o);   // 16B aligned: 12*(2048r+4c)
    __builtin_nontemporal_store(v0, o4 + 0);
    __builtin_nontemporal_store(v1, o4 + 1);
    __builtin_nontemporal_store(v2, o4 + 2);
}

extern "C" void kernel_launch(void* const* d_in, const int* in_sizes, int n_in,
                              void* d_out, int out_size, void* d_ws, size_t ws_size,
                              hipStream_t stream) {
    const float* x = (const float*)d_in[0];
    float* out = (float*)d_out;
    dim3 grid(WW / TILE, HH / TILE);  // 64 x 64 = 4096 blocks
    dim3 block(256);
    UnfoldPlainFit_42477226558039_kernel<<<grid, block, 0, stream>>>(x, out);
}

// Round 5
// 92.362 us; speedup vs baseline: 1.0698x; 1.0698x over previous
//
#include <hip/hip_runtime.h>

#define HH 2048
#define WW 2048
#define KK 7
#define PADK 3
#define TILE 64              // 64x64 outputs per block
#define PADT (TILE + 6)      // 70 padded rows
#define HSW 68               // LDS float stride (mult of 4, not pow2)

typedef float v4f __attribute__((ext_vector_type(4)));

__global__ __launch_bounds__(256)
void UnfoldPlainFit_42477226558039_kernel(const float* __restrict__ x,
                                          float* __restrict__ out) {
    // Hs/Hx only — no staged input tile. 2 * 70 * 68 * 4 B = 38,080 B
    // -> 4 blocks/CU by LDS (160 KiB), grid is exactly 4 blocks/CU.
    __shared__ float sHs[PADT][HSW];
    __shared__ float sHx[PADT][HSW];

    const int bx = blockIdx.x, by = blockIdx.y;
    const int tileR = by * TILE, tileC = bx * TILE;
    const int tid = threadIdx.x;

    // ---- Stage A: horizontal sums straight from global ----
    // item (lr, u): padded row lr (global row clamp(tileR-3+lr)), output cols
    // tileC+4u .. +3. Needs x cols tileC+4u-3 .. +7 -> three aligned float4
    // loads covering tileC+4u-4 .. +11. Neighboring u overlap 2/3 -> L1 hit.
    const bool interior = (bx > 0) & (bx < (WW / TILE - 1));
    if (interior) {
#pragma unroll
        for (int it = 0; it < 5; ++it) {
            int idx = tid + it * 256;
            if (idx < PADT * 16) {
                int lr = idx >> 4;
                int u  = idx & 15;
                int gr = max(0, min(HH - 1, tileR - PADK + lr));
                const v4f* p = reinterpret_cast<const v4f*>(
                    x + (size_t)gr * WW + (tileC + 4 * u - 4));
                v4f a = p[0], b = p[1], c = p[2];
                float w[12] = {a.x, a.y, a.z, a.w, b.x, b.y, b.z, b.w,
                               c.x, c.y, c.z, c.w};
                v4f hs, hx;
#pragma unroll
                for (int t = 0; t < 4; ++t) {
                    float s = 0.f, wx = 0.f;
#pragma unroll
                    for (int m = 0; m < KK; ++m) {
                        float v = w[1 + t + m];
                        s += v;
                        wx = fmaf((float)(m - PADK), v, wx);
                    }
                    hs[t] = s;
                    hx[t] = wx;
                }
                reinterpret_cast<v4f*>(&sHs[lr][0])[u] = hs;
                reinterpret_cast<v4f*>(&sHx[lr][0])[u] = hx;
            }
        }
    } else {
        // column-edge tiles (64 of 1024): scalar clamped loads
        for (int idx = tid; idx < PADT * 16; idx += 256) {
            int lr = idx >> 4;
            int u  = idx & 15;
            int gr = max(0, min(HH - 1, tileR - PADK + lr));
            const float* rowp = x + (size_t)gr * WW;
            float w[12];
#pragma unroll
            for (int j = 0; j < 12; ++j) {
                int gc = max(0, min(WW - 1, tileC + 4 * u - 4 + j));
                w[j] = rowp[gc];
            }
            v4f hs, hx;
#pragma unroll
            for (int t = 0; t < 4; ++t) {
                float s = 0.f, wx = 0.f;
#pragma unroll
                for (int m = 0; m < KK; ++m) {
                    float v = w[1 + t + m];
                    s += v;
                    wx = fmaf((float)(m - PADK), v, wx);
                }
                hs[t] = s;
                hx[t] = wx;
            }
            reinterpret_cast<v4f*>(&sHs[lr][0])[u] = hs;
            reinterpret_cast<v4f*>(&sHx[lr][0])[u] = hx;
        }
    }
    __syncthreads();

    // ---- Stage B: vertical combine, 1x16 strip per thread ----
    const int row = tid >> 2;        // 0..63
    const int ug  = tid & 3;         // 16-col group
    float c0[16], c1[16], c2[16];
#pragma unroll
    for (int t = 0; t < 16; ++t) { c0[t] = 0.f; c1[t] = 0.f; c2[t] = 0.f; }

#pragma unroll
    for (int i = 0; i < KK; ++i) {
        float wy = (float)(i - PADK);
        const v4f* hs4 = reinterpret_cast<const v4f*>(&sHs[row + i][0]) + 4 * ug;
        const v4f* hx4 = reinterpret_cast<const v4f*>(&sHx[row + i][0]) + 4 * ug;
#pragma unroll
        for (int j = 0; j < 4; ++j) {
            v4f hs = hs4[j], hx = hx4[j];
#pragma unroll
            for (int t = 0; t < 4; ++t) {
                int k = 4 * j + t;
                c2[k] += hs[t];
                c1[k] = fmaf(wy, hs[t], c1[k]);
                c0[k] += hx[t];
            }
        }
    }

    const float W196 = 1.0f / 196.0f;   // sum(x^2) over 7x7 grid = 196
    const float W49  = 1.0f / 49.0f;

    // 16 pixels * 3 floats = 192 contiguous bytes per thread, 16B aligned.
    float* o = out + ((size_t)(tileR + row) * WW + tileC + 16 * ug) * 3;
    v4f* o4 = reinterpret_cast<v4f*>(o);
#pragma unroll
    for (int g = 0; g < 4; ++g) {      // 4 pixels -> 3 float4 per group
        int k = 4 * g;
        v4f v0 = {c0[k+0] * W196, c1[k+0] * W196, c2[k+0] * W49,  c0[k+1] * W196};
        v4f v1 = {c1[k+1] * W196, c2[k+1] * W49,  c0[k+2] * W196, c1[k+2] * W196};
        v4f v2 = {c2[k+2] * W49,  c0[k+3] * W196, c1[k+3] * W196, c2[k+3] * W49};
        o4[3 * g + 0] = v0;
        o4[3 * g + 1] = v1;
        o4[3 * g + 2] = v2;
    }
}

extern "C" void kernel_launch(void* const* d_in, const int* in_sizes, int n_in,
                              void* d_out, int out_size, void* d_ws, size_t ws_size,
                              hipStream_t stream) {
    const float* x = (const float*)d_in[0];
    float* out = (float*)d_out;
    dim3 grid(WW / TILE, HH / TILE);  // 32 x 32 = 1024 blocks = 4/CU
    dim3 block(256);
    UnfoldPlainFit_42477226558039_kernel<<<grid, block, 0, stream>>>(x, out);
}

// Round 6
// 89.186 us; speedup vs baseline: 1.1078x; 1.0356x over previous
//
#include <hip/hip_runtime.h>

#define HH 2048
#define WW 2048
#define KK 7
#define PADK 3
#define TILE 32
#define PADT (TILE + 6)      // 38 padded rows
#define HSW 36               // LDS float stride: b128-aligned, stride%32=4
                             // -> b128 rows land on even 8-lane/bank floor

typedef float v4f __attribute__((ext_vector_type(4)));

__global__ __launch_bounds__(256)
void UnfoldPlainFit_42477226558039_kernel(const float* __restrict__ x,
                                          float* __restrict__ out) {
    // Only horizontal sums live in LDS: 2 * 38 * 36 * 4 B = 10,944 B
    // -> occupancy wave-limited at 8 blocks/CU (grid 4096 = 16/CU waves of work)
    __shared__ float sHs[PADT][HSW];
    __shared__ float sHx[PADT][HSW];

    const int bx = blockIdx.x, by = blockIdx.y;
    const int tileR = by * TILE, tileC = bx * TILE;
    const int tid = threadIdx.x;

    // ---- Stage A: horizontal sums straight from global ----
    // item (lr,u): padded row lr, output cols tileC+4u..+3. Window cols
    // tileC+4u-4 .. +11 via three aligned dwordx4 loads; neighbor items
    // overlap 2/3 of their loads -> L1 hits, HBM sees each line once.
    const bool interior = (bx > 0) & (bx < (WW / TILE - 1));
    if (interior) {
#pragma unroll
        for (int it = 0; it < 2; ++it) {
            int idx = tid + it * 256;
            if (idx < PADT * 8) {
                int lr = idx >> 3;
                int u  = idx & 7;
                int gr = max(0, min(HH - 1, tileR - PADK + lr));
                const v4f* p = reinterpret_cast<const v4f*>(
                    x + (size_t)gr * WW + (tileC + 4 * u - 4));
                v4f a = p[0], b = p[1], c = p[2];
                float w[12] = {a.x, a.y, a.z, a.w, b.x, b.y, b.z, b.w,
                               c.x, c.y, c.z, c.w};
                v4f hs, hx;
#pragma unroll
                for (int t = 0; t < 4; ++t) {
                    float s = 0.f, wx = 0.f;
#pragma unroll
                    for (int m = 0; m < KK; ++m) {   // col weight = m-3
                        float v = w[1 + t + m];
                        s += v;
                        wx = fmaf((float)(m - PADK), v, wx);
                    }
                    hs[t] = s;
                    hx[t] = wx;
                }
                reinterpret_cast<v4f*>(&sHs[lr][0])[u] = hs;
                reinterpret_cast<v4f*>(&sHx[lr][0])[u] = hx;
            }
        }
    } else {
        // 128 column-edge blocks: scalar clamped loads
        for (int idx = tid; idx < PADT * 8; idx += 256) {
            int lr = idx >> 3;
            int u  = idx & 7;
            int gr = max(0, min(HH - 1, tileR - PADK + lr));
            const float* rowp = x + (size_t)gr * WW;
            float w[12];
#pragma unroll
            for (int j = 0; j < 12; ++j) {
                int gc = max(0, min(WW - 1, tileC + 4 * u - 4 + j));
                w[j] = rowp[gc];
            }
            v4f hs, hx;
#pragma unroll
            for (int t = 0; t < 4; ++t) {
                float s = 0.f, wx = 0.f;
#pragma unroll
                for (int m = 0; m < KK; ++m) {
                    float v = w[1 + t + m];
                    s += v;
                    wx = fmaf((float)(m - PADK), v, wx);
                }
                hs[t] = s;
                hx[t] = wx;
            }
            reinterpret_cast<v4f*>(&sHs[lr][0])[u] = hs;
            reinterpret_cast<v4f*>(&sHx[lr][0])[u] = hx;
        }
    }
    __syncthreads();   // the only barrier

    // ---- Stage B: vertical combine, 1x4 strip per thread, b128 reads ----
    const int row = tid >> 3;          // 0..31
    const int u   = tid & 7;           // float4 group
    float c0[4] = {0.f, 0.f, 0.f, 0.f};
    float c1[4] = {0.f, 0.f, 0.f, 0.f};
    float c2[4] = {0.f, 0.f, 0.f, 0.f};
#pragma unroll
    for (int i = 0; i < KK; ++i) {
        v4f hs = reinterpret_cast<const v4f*>(&sHs[row + i][0])[u];
        v4f hx = reinterpret_cast<const v4f*>(&sHx[row + i][0])[u];
        float wy = (float)(i - PADK);    // row weight
#pragma unroll
        for (int t = 0; t < 4; ++t) {
            c2[t] += hs[t];
            c1[t] = fmaf(wy, hs[t], c1[t]);
            c0[t] += hx[t];
        }
    }
    const float W196 = 1.0f / 196.0f;   // sum(x^2) over 7x7 grid = 196
    const float W49  = 1.0f / 49.0f;

    // 4 pixels * 3 floats = 48 contiguous B/thread, 16B aligned.
    float* o = out + ((size_t)(tileR + row) * WW + tileC + 4 * u) * 3;
    v4f* o4 = reinterpret_cast<v4f*>(o);
    v4f v0 = {c0[0] * W196, c1[0] * W196, c2[0] * W49,  c0[1] * W196};
    v4f v1 = {c1[1] * W196, c2[1] * W49,  c0[2] * W196, c1[2] * W196};
    v4f v2 = {c2[2] * W49,  c0[3] * W196, c1[3] * W196, c2[3] * W49};
    o4[0] = v0;
    o4[1] = v1;
    o4[2] = v2;
}

extern "C" void kernel_launch(void* const* d_in, const int* in_sizes, int n_in,
                              void* d_out, int out_size, void* d_ws, size_t ws_size,
                              hipStream_t stream) {
    const float* x = (const float*)d_in[0];
    float* out = (float*)d_out;
    dim3 grid(WW / TILE, HH / TILE);  // 64 x 64 = 4096 blocks
    dim3 block(256);
    UnfoldPlainFit_42477226558039_kernel<<<grid, block, 0, stream>>>(x, out);
}